// Round 2
// baseline (1782.783 us; speedup 1.0000x reference)
//
#include <hip/hip_runtime.h>
#include <hip/hip_bf16.h>

#define NN    100000
#define EE    1600000
#define ETOT  (EE + NN)
#define INF   56
#define TFEAT 16
#define K1    72

// relaxed agent-scope f32 atomic add -> global_atomic_add_f32 on gfx950
__device__ __forceinline__ void fatomic_add(float* p, float v) {
    __hip_atomic_fetch_add(p, v, __ATOMIC_RELAXED, __HIP_MEMORY_SCOPE_AGENT);
}

__device__ __forceinline__ float lrelu(float v) { return v > 0.f ? v : 0.2f * v; }

// h = xc @ W  (xc = [x | relu(temporal*Wt+bt)] for layer 1, x1 for layer 2)
// also s[n,h] = <h_row, a_src[h]>, d[n,h] = <h_row, a_dst[h]>
// block = 256 threads = 4 nodes x 64 outputs; one wave per node.
template <int K, bool TEMPORAL>
__global__ void __launch_bounds__(256) feat_kernel(
    const float* __restrict__ xin, const float* __restrict__ temp,
    const float* __restrict__ Wt, const float* __restrict__ bt,
    const float* __restrict__ W, const float* __restrict__ asrc,
    const float* __restrict__ adst,
    float* __restrict__ h, float* __restrict__ s, float* __restrict__ d)
{
    __shared__ float Wl[K * 64];
    __shared__ float xc[4 * K];
    const int tid = threadIdx.x;
    const int n0 = blockIdx.x * 4;

    for (int i = tid; i < K * 64; i += 256) Wl[i] = W[i];

    if (TEMPORAL) {
        if (tid < 4 * INF) {
            int node = tid / INF, k = tid - node * INF;
            xc[node * K + k] = xin[(n0 + node) * INF + k];
        }
        if (tid < 4 * TFEAT) {
            int node = tid >> 4, j = tid & 15;
            float tv = temp[n0 + node] * Wt[j] + bt[j];
            xc[node * K + INF + j] = tv > 0.f ? tv : 0.f;
        }
    } else {
        int node = tid >> 6, k = tid & 63;
        xc[node * K + k] = xin[(n0 + node) * 64 + k];
    }
    __syncthreads();

    const int node = tid >> 6, out = tid & 63;
    float acc = 0.f;
#pragma unroll
    for (int k = 0; k < K; k++) acc += xc[node * K + k] * Wl[k * 64 + out];

    const int gn = n0 + node;
    h[gn * 64 + out] = acc;

    const int head = out >> 4, c = out & 15;
    float vs = acc * asrc[head * 16 + c];
    float vd = acc * adst[head * 16 + c];
#pragma unroll
    for (int o = 8; o; o >>= 1) {
        vs += __shfl_down(vs, o, 16);
        vd += __shfl_down(vd, o, 16);
    }
    if (c == 0) { s[gn * 4 + head] = vs; d[gn * 4 + head] = vd; }
}

// pass 1: z[dst,h] += exp(lrelu(s[src,h]+d[dst,h]))   one thread per (edge, head)
__global__ void __launch_bounds__(256) edge_z_kernel(
    const int* __restrict__ esrc, const int* __restrict__ edst,
    const float* __restrict__ s, const float* __restrict__ d,
    float* __restrict__ z)
{
    int t = blockIdx.x * 256 + threadIdx.x;
    if (t >= 4 * ETOT) return;
    int e = t >> 2, head = t & 3;
    int sn, dn;
    if (e < EE) { sn = esrc[e]; dn = edst[e]; } else { sn = dn = e - EE; }
    float v = lrelu(s[sn * 4 + head] + d[dn * 4 + head]);
    fatomic_add(&z[dn * 4 + head], __expf(v));
}

// pass 2: agg[dst,c] += alpha_e[head(c)] * h[src,c]   one wave per edge, lane = channel
__global__ void __launch_bounds__(256) edge_agg_kernel(
    const int* __restrict__ esrc, const int* __restrict__ edst,
    const float* __restrict__ s, const float* __restrict__ d,
    const float* __restrict__ z, const float* __restrict__ h,
    float* __restrict__ agg)
{
    int wave = (blockIdx.x * 256 + threadIdx.x) >> 6;
    int lane = threadIdx.x & 63;
    if (wave >= ETOT) return;
    int sn, dn;
    if (wave < EE) { sn = esrc[wave]; dn = edst[wave]; } else { sn = dn = wave - EE; }
    int head = lane >> 4;
    float v = lrelu(s[sn * 4 + head] + d[dn * 4 + head]);
    float alpha = __expf(v) / (z[dn * 4 + head] + 1e-16f);
    fatomic_add(&agg[dn * 64 + lane], alpha * h[sn * 64 + lane]);
}

// layernorm + relu -> f32 (layer 1).  one wave per node.
__global__ void __launch_bounds__(256) ln_relu_f32_kernel(
    const float* __restrict__ agg, const float* __restrict__ bias,
    const float* __restrict__ gamma, const float* __restrict__ beta,
    float* __restrict__ out)
{
    int n = blockIdx.x * 4 + (threadIdx.x >> 6);
    int c = threadIdx.x & 63;
    float v = agg[n * 64 + c] + bias[c];
    float sum = v, sq = v * v;
#pragma unroll
    for (int o = 32; o; o >>= 1) { sum += __shfl_xor(sum, o); sq += __shfl_xor(sq, o); }
    float mu = sum * (1.f / 64.f);
    float var = sq * (1.f / 64.f) - mu * mu;
    float y = (v - mu) * rsqrtf(var + 1e-5f) * gamma[c] + beta[c];
    out[n * 64 + c] = y > 0.f ? y : 0.f;
}

// layernorm + relu -> f32 output + per-block partial sums for the global mean.
// block = 256 = 4 nodes.
__global__ void __launch_bounds__(256) ln2_kernel(
    const float* __restrict__ agg, const float* __restrict__ bias,
    const float* __restrict__ gamma, const float* __restrict__ beta,
    float* __restrict__ out, float* __restrict__ meanacc)
{
    __shared__ float sd[4 * 64];
    int wid = threadIdx.x >> 6, c = threadIdx.x & 63;
    int n = blockIdx.x * 4 + wid;
    float v = agg[n * 64 + c] + bias[c];
    float sum = v, sq = v * v;
#pragma unroll
    for (int o = 32; o; o >>= 1) { sum += __shfl_xor(sum, o); sq += __shfl_xor(sq, o); }
    float mu = sum * (1.f / 64.f);
    float var = sq * (1.f / 64.f) - mu * mu;
    float y = (v - mu) * rsqrtf(var + 1e-5f) * gamma[c] + beta[c];
    y = y > 0.f ? y : 0.f;
    out[n * 64 + c] = y;
    sd[wid * 64 + c] = y;
    __syncthreads();
    if (threadIdx.x < 64) {
        float p = 0.f;
#pragma unroll
        for (int w = 0; w < 4; w++) p += sd[w * 64 + threadIdx.x];
        fatomic_add(&meanacc[threadIdx.x], p);
    }
}

// ge = relu(mean @ Wp1 + bp1) @ Wp2 + bp2  -> f32 out[6400000..6400063]
__global__ void __launch_bounds__(64) mlp_kernel(
    const float* __restrict__ meanacc,
    const float* __restrict__ Wp1, const float* __restrict__ bp1,
    const float* __restrict__ Wp2, const float* __restrict__ bp2,
    float* __restrict__ out)
{
    __shared__ float mean[64], hid[64];
    int t = threadIdx.x;
    mean[t] = meanacc[t] * (1.f / (float)NN);
    __syncthreads();
    float acc = bp1[t];
#pragma unroll
    for (int i = 0; i < 64; i++) acc += mean[i] * Wp1[i * 64 + t];
    hid[t] = acc > 0.f ? acc : 0.f;
    __syncthreads();
    float o = bp2[t];
#pragma unroll
    for (int i = 0; i < 64; i++) o += hid[i] * Wp2[i * 64 + t];
    out[NN * 64 + t] = o;
}

extern "C" void kernel_launch(void* const* d_in, const int* in_sizes, int n_in,
                              void* d_out, int out_size, void* d_ws, size_t ws_size,
                              hipStream_t stream) {
    const float* x    = (const float*)d_in[0];
    const float* temp = (const float*)d_in[1];
    const int*   ei   = (const int*)d_in[2];
    const float* Wt   = (const float*)d_in[3];
    const float* bt   = (const float*)d_in[4];
    const float* W1   = (const float*)d_in[5];
    const float* as1  = (const float*)d_in[6];
    const float* ad1  = (const float*)d_in[7];
    const float* b1   = (const float*)d_in[8];
    const float* g1   = (const float*)d_in[9];
    const float* be1  = (const float*)d_in[10];
    const float* W2   = (const float*)d_in[11];
    const float* as2  = (const float*)d_in[12];
    const float* ad2  = (const float*)d_in[13];
    const float* b2   = (const float*)d_in[14];
    const float* g2   = (const float*)d_in[15];
    const float* be2  = (const float*)d_in[16];
    const float* Wp1  = (const float*)d_in[17];
    const float* bp1  = (const float*)d_in[18];
    const float* Wp2  = (const float*)d_in[19];
    const float* bp2  = (const float*)d_in[20];

    float* out = (float*)d_out;   // reference outputs are float32

    // ws layout (floats): h 6.4M | agg 6.4M | x1 6.4M | s 400k | d 400k | z 400k | meanacc 64
    float* ws      = (float*)d_ws;
    float* h       = ws;
    float* agg     = ws + 6400000;
    float* x1      = ws + 12800000;
    float* sbuf    = ws + 19200000;
    float* dbuf    = sbuf + 400000;
    float* zbuf    = dbuf + 400000;
    float* meanacc = zbuf + 400000;

    const int* esrc = ei;
    const int* edst = ei + EE;

    const int zgrid = (4 * ETOT + 255) / 256;   // pass-1 threads
    const int agrid = (ETOT + 3) / 4;           // pass-2 waves, 4 per block

    // ---- layer 1 ----
    hipMemsetAsync(zbuf, 0, 400000 * sizeof(float), stream);
    hipMemsetAsync(agg, 0, 6400000 * sizeof(float), stream);
    hipMemsetAsync(meanacc, 0, 64 * sizeof(float), stream);

    feat_kernel<K1, true><<<NN / 4, 256, 0, stream>>>(x, temp, Wt, bt, W1, as1, ad1, h, sbuf, dbuf);
    edge_z_kernel<<<zgrid, 256, 0, stream>>>(esrc, edst, sbuf, dbuf, zbuf);
    edge_agg_kernel<<<agrid, 256, 0, stream>>>(esrc, edst, sbuf, dbuf, zbuf, h, agg);
    ln_relu_f32_kernel<<<NN / 4, 256, 0, stream>>>(agg, b1, g1, be1, x1);

    // ---- layer 2 ----
    hipMemsetAsync(zbuf, 0, 400000 * sizeof(float), stream);
    hipMemsetAsync(agg, 0, 6400000 * sizeof(float), stream);

    feat_kernel<64, false><<<NN / 4, 256, 0, stream>>>(x1, nullptr, nullptr, nullptr, W2, as2, ad2, h, sbuf, dbuf);
    edge_z_kernel<<<zgrid, 256, 0, stream>>>(esrc, edst, sbuf, dbuf, zbuf);
    edge_agg_kernel<<<agrid, 256, 0, stream>>>(esrc, edst, sbuf, dbuf, zbuf, h, agg);
    ln2_kernel<<<NN / 4, 256, 0, stream>>>(agg, b2, g2, be2, out, meanacc);

    // ---- global mean MLP ----
    mlp_kernel<<<1, 64, 0, stream>>>(meanacc, Wp1, bp1, Wp2, bp2, out);
}

// Round 3
// 1220.052 us; speedup vs baseline: 1.4612x; 1.4612x over previous
//
#include <hip/hip_runtime.h>
#include <hip/hip_bf16.h>

#define NN    100000
#define EE    1600000
#define ETOT  (EE + NN)
#define INF   56
#define TFEAT 16
#define K1    72

// relaxed agent-scope f32 atomic add -> global_atomic_add_f32 on gfx950
__device__ __forceinline__ void fatomic_add(float* p, float v) {
    __hip_atomic_fetch_add(p, v, __ATOMIC_RELAXED, __HIP_MEMORY_SCOPE_AGENT);
}

__device__ __forceinline__ float lrelu(float v) { return v > 0.f ? v : 0.2f * v; }

// h = xc @ W  (xc = [x | relu(temporal*Wt+bt)] for layer 1, x1 for layer 2)
// also s[n,h] = <h_row, a_src[h]>, d[n,h] = <h_row, a_dst[h]>
// block = 256 threads = 4 nodes x 64 outputs; one wave per node.
template <int K, bool TEMPORAL>
__global__ void __launch_bounds__(256) feat_kernel(
    const float* __restrict__ xin, const float* __restrict__ temp,
    const float* __restrict__ Wt, const float* __restrict__ bt,
    const float* __restrict__ W, const float* __restrict__ asrc,
    const float* __restrict__ adst,
    float* __restrict__ h, float* __restrict__ s, float* __restrict__ d)
{
    __shared__ float Wl[K * 64];
    __shared__ float xc[4 * K];
    const int tid = threadIdx.x;
    const int n0 = blockIdx.x * 4;

    for (int i = tid; i < K * 64; i += 256) Wl[i] = W[i];

    if (TEMPORAL) {
        if (tid < 4 * INF) {
            int node = tid / INF, k = tid - node * INF;
            xc[node * K + k] = xin[(n0 + node) * INF + k];
        }
        if (tid < 4 * TFEAT) {
            int node = tid >> 4, j = tid & 15;
            float tv = temp[n0 + node] * Wt[j] + bt[j];
            xc[node * K + INF + j] = tv > 0.f ? tv : 0.f;
        }
    } else {
        int node = tid >> 6, k = tid & 63;
        xc[node * K + k] = xin[(n0 + node) * 64 + k];
    }
    __syncthreads();

    const int node = tid >> 6, out = tid & 63;
    float acc = 0.f;
#pragma unroll
    for (int k = 0; k < K; k++) acc += xc[node * K + k] * Wl[k * 64 + out];

    const int gn = n0 + node;
    h[gn * 64 + out] = acc;

    const int head = out >> 4, c = out & 15;
    float vs = acc * asrc[head * 16 + c];
    float vd = acc * adst[head * 16 + c];
#pragma unroll
    for (int o = 8; o; o >>= 1) {
        vs += __shfl_down(vs, o, 16);
        vd += __shfl_down(vd, o, 16);
    }
    if (c == 0) { s[gn * 4 + head] = vs; d[gn * 4 + head] = vd; }
}

// pass 1: z[dst,h] += exp(lrelu(s[src,h]+d[dst,h]))   one thread per (edge, head)
__global__ void __launch_bounds__(256) edge_z_kernel(
    const int* __restrict__ esrc, const int* __restrict__ edst,
    const float* __restrict__ s, const float* __restrict__ d,
    float* __restrict__ z)
{
    int t = blockIdx.x * 256 + threadIdx.x;
    if (t >= 4 * ETOT) return;
    int e = t >> 2, head = t & 3;
    int sn, dn;
    if (e < EE) { sn = esrc[e]; dn = edst[e]; } else { sn = dn = e - EE; }
    float v = lrelu(s[sn * 4 + head] + d[dn * 4 + head]);
    fatomic_add(&z[dn * 4 + head], __expf(v));
}

// pass 2: agg[dst,c] += alpha_e[head(c)] * h[src,c]   one wave per edge, lane = channel
__global__ void __launch_bounds__(256) edge_agg_kernel(
    const int* __restrict__ esrc, const int* __restrict__ edst,
    const float* __restrict__ s, const float* __restrict__ d,
    const float* __restrict__ z, const float* __restrict__ h,
    float* __restrict__ agg)
{
    int wave = (blockIdx.x * 256 + threadIdx.x) >> 6;
    int lane = threadIdx.x & 63;
    if (wave >= ETOT) return;
    int sn, dn;
    if (wave < EE) { sn = esrc[wave]; dn = edst[wave]; } else { sn = dn = wave - EE; }
    int head = lane >> 4;
    float v = lrelu(s[sn * 4 + head] + d[dn * 4 + head]);
    float alpha = __expf(v) / (z[dn * 4 + head] + 1e-16f);
    fatomic_add(&agg[dn * 64 + lane], alpha * h[sn * 64 + lane]);
}

// layernorm + relu -> f32 (layer 1).  one wave per node.
__global__ void __launch_bounds__(256) ln_relu_f32_kernel(
    const float* __restrict__ agg, const float* __restrict__ bias,
    const float* __restrict__ gamma, const float* __restrict__ beta,
    float* __restrict__ out)
{
    int n = blockIdx.x * 4 + (threadIdx.x >> 6);
    int c = threadIdx.x & 63;
    float v = agg[n * 64 + c] + bias[c];
    float sum = v, sq = v * v;
#pragma unroll
    for (int o = 32; o; o >>= 1) { sum += __shfl_xor(sum, o); sq += __shfl_xor(sq, o); }
    float mu = sum * (1.f / 64.f);
    float var = sq * (1.f / 64.f) - mu * mu;
    float y = (v - mu) * rsqrtf(var + 1e-5f) * gamma[c] + beta[c];
    out[n * 64 + c] = y > 0.f ? y : 0.f;
}

// layernorm + relu -> f32 output + hierarchical partial sums for the global mean.
// grid-stride over node groups; ONE atomic per channel per block (contention fix).
#define LN2_GRID 512
__global__ void __launch_bounds__(256) ln2_kernel(
    const float* __restrict__ agg, const float* __restrict__ bias,
    const float* __restrict__ gamma, const float* __restrict__ beta,
    float* __restrict__ out, float* __restrict__ meanacc)
{
    __shared__ float sd[4 * 64];
    const int wid = threadIdx.x >> 6, c = threadIdx.x & 63;
    const float bc = bias[c], gc = gamma[c], bec = beta[c];
    float csum = 0.f;
    for (int grp = blockIdx.x; grp < NN / 4; grp += LN2_GRID) {
        int n = grp * 4 + wid;
        float v = agg[n * 64 + c] + bc;
        float sum = v, sq = v * v;
#pragma unroll
        for (int o = 32; o; o >>= 1) { sum += __shfl_xor(sum, o); sq += __shfl_xor(sq, o); }
        float mu = sum * (1.f / 64.f);
        float var = sq * (1.f / 64.f) - mu * mu;
        float y = (v - mu) * rsqrtf(var + 1e-5f) * gc + bec;
        y = y > 0.f ? y : 0.f;
        out[n * 64 + c] = y;
        csum += y;
    }
    sd[wid * 64 + c] = csum;
    __syncthreads();
    if (threadIdx.x < 64) {
        float p = sd[threadIdx.x] + sd[64 + threadIdx.x] + sd[128 + threadIdx.x] + sd[192 + threadIdx.x];
        fatomic_add(&meanacc[threadIdx.x], p);
    }
}

// ge = relu(mean @ Wp1 + bp1) @ Wp2 + bp2  -> f32 out[6400000..6400063]
__global__ void __launch_bounds__(64) mlp_kernel(
    const float* __restrict__ meanacc,
    const float* __restrict__ Wp1, const float* __restrict__ bp1,
    const float* __restrict__ Wp2, const float* __restrict__ bp2,
    float* __restrict__ out)
{
    __shared__ float mean[64], hid[64];
    int t = threadIdx.x;
    mean[t] = meanacc[t] * (1.f / (float)NN);
    __syncthreads();
    float acc = bp1[t];
#pragma unroll
    for (int i = 0; i < 64; i++) acc += mean[i] * Wp1[i * 64 + t];
    hid[t] = acc > 0.f ? acc : 0.f;
    __syncthreads();
    float o = bp2[t];
#pragma unroll
    for (int i = 0; i < 64; i++) o += hid[i] * Wp2[i * 64 + t];
    out[NN * 64 + t] = o;
}

extern "C" void kernel_launch(void* const* d_in, const int* in_sizes, int n_in,
                              void* d_out, int out_size, void* d_ws, size_t ws_size,
                              hipStream_t stream) {
    const float* x    = (const float*)d_in[0];
    const float* temp = (const float*)d_in[1];
    const int*   ei   = (const int*)d_in[2];
    const float* Wt   = (const float*)d_in[3];
    const float* bt   = (const float*)d_in[4];
    const float* W1   = (const float*)d_in[5];
    const float* as1  = (const float*)d_in[6];
    const float* ad1  = (const float*)d_in[7];
    const float* b1   = (const float*)d_in[8];
    const float* g1   = (const float*)d_in[9];
    const float* be1  = (const float*)d_in[10];
    const float* W2   = (const float*)d_in[11];
    const float* as2  = (const float*)d_in[12];
    const float* ad2  = (const float*)d_in[13];
    const float* b2   = (const float*)d_in[14];
    const float* g2   = (const float*)d_in[15];
    const float* be2  = (const float*)d_in[16];
    const float* Wp1  = (const float*)d_in[17];
    const float* bp1  = (const float*)d_in[18];
    const float* Wp2  = (const float*)d_in[19];
    const float* bp2  = (const float*)d_in[20];

    float* out = (float*)d_out;   // reference outputs are float32

    // ws layout (floats): h 6.4M | agg 6.4M | x1 6.4M | s 400k | d 400k | z 400k | meanacc 64
    float* ws      = (float*)d_ws;
    float* h       = ws;
    float* agg     = ws + 6400000;
    float* x1      = ws + 12800000;
    float* sbuf    = ws + 19200000;
    float* dbuf    = sbuf + 400000;
    float* zbuf    = dbuf + 400000;
    float* meanacc = zbuf + 400000;

    const int* esrc = ei;
    const int* edst = ei + EE;

    const int zgrid = (4 * ETOT + 255) / 256;   // pass-1 threads
    const int agrid = (ETOT + 3) / 4;           // pass-2 waves, 4 per block

    // ---- layer 1 ----
    hipMemsetAsync(zbuf, 0, 400000 * sizeof(float), stream);
    hipMemsetAsync(agg, 0, 6400000 * sizeof(float), stream);
    hipMemsetAsync(meanacc, 0, 64 * sizeof(float), stream);

    feat_kernel<K1, true><<<NN / 4, 256, 0, stream>>>(x, temp, Wt, bt, W1, as1, ad1, h, sbuf, dbuf);
    edge_z_kernel<<<zgrid, 256, 0, stream>>>(esrc, edst, sbuf, dbuf, zbuf);
    edge_agg_kernel<<<agrid, 256, 0, stream>>>(esrc, edst, sbuf, dbuf, zbuf, h, agg);
    ln_relu_f32_kernel<<<NN / 4, 256, 0, stream>>>(agg, b1, g1, be1, x1);

    // ---- layer 2 ----
    hipMemsetAsync(zbuf, 0, 400000 * sizeof(float), stream);
    hipMemsetAsync(agg, 0, 6400000 * sizeof(float), stream);

    feat_kernel<64, false><<<NN / 4, 256, 0, stream>>>(x1, nullptr, nullptr, nullptr, W2, as2, ad2, h, sbuf, dbuf);
    edge_z_kernel<<<zgrid, 256, 0, stream>>>(esrc, edst, sbuf, dbuf, zbuf);
    edge_agg_kernel<<<agrid, 256, 0, stream>>>(esrc, edst, sbuf, dbuf, zbuf, h, agg);
    ln2_kernel<<<LN2_GRID, 256, 0, stream>>>(agg, b2, g2, be2, out, meanacc);

    // ---- global mean MLP ----
    mlp_kernel<<<1, 64, 0, stream>>>(meanacc, Wp1, bp1, Wp2, bp2, out);
}

// Round 4
// 604.652 us; speedup vs baseline: 2.9484x; 2.0178x over previous
//
#include <hip/hip_runtime.h>
#include <hip/hip_bf16.h>

#define NN    100000
#define EE    1600000
#define ETOT  (EE + NN)
#define INF   56
#define TFEAT 16
#define K1    72
#define SCAN_BLK 512
#define SCAN_NB  ((NN + SCAN_BLK - 1) / SCAN_BLK)

__device__ __forceinline__ void fatomic_add(float* p, float v) {
    __hip_atomic_fetch_add(p, v, __ATOMIC_RELAXED, __HIP_MEMORY_SCOPE_AGENT);
}

__device__ __forceinline__ float lrelu(float v) { return v > 0.f ? v : 0.2f * v; }

// ---------------- dense feature transform (unchanged) ----------------
// h = xc @ W ; s[n,h] = <h_row, a_src[h]> ; d[n,h] = <h_row, a_dst[h]>
template <int K, bool TEMPORAL>
__global__ void __launch_bounds__(256) feat_kernel(
    const float* __restrict__ xin, const float* __restrict__ temp,
    const float* __restrict__ Wt, const float* __restrict__ bt,
    const float* __restrict__ W, const float* __restrict__ asrc,
    const float* __restrict__ adst,
    float* __restrict__ h, float* __restrict__ s, float* __restrict__ d)
{
    __shared__ float Wl[K * 64];
    __shared__ float xc[4 * K];
    const int tid = threadIdx.x;
    const int n0 = blockIdx.x * 4;

    for (int i = tid; i < K * 64; i += 256) Wl[i] = W[i];

    if (TEMPORAL) {
        if (tid < 4 * INF) {
            int node = tid / INF, k = tid - node * INF;
            xc[node * K + k] = xin[(n0 + node) * INF + k];
        }
        if (tid < 4 * TFEAT) {
            int node = tid >> 4, j = tid & 15;
            float tv = temp[n0 + node] * Wt[j] + bt[j];
            xc[node * K + INF + j] = tv > 0.f ? tv : 0.f;
        }
    } else {
        int node = tid >> 6, k = tid & 63;
        xc[node * K + k] = xin[(n0 + node) * 64 + k];
    }
    __syncthreads();

    const int node = tid >> 6, out = tid & 63;
    float acc = 0.f;
#pragma unroll
    for (int k = 0; k < K; k++) acc += xc[node * K + k] * Wl[k * 64 + out];

    const int gn = n0 + node;
    h[gn * 64 + out] = acc;

    const int head = out >> 4, c = out & 15;
    float vs = acc * asrc[head * 16 + c];
    float vd = acc * adst[head * 16 + c];
#pragma unroll
    for (int o = 8; o; o >>= 1) {
        vs += __shfl_down(vs, o, 16);
        vd += __shfl_down(vd, o, 16);
    }
    if (c == 0) { s[gn * 4 + head] = vs; d[gn * 4 + head] = vd; }
}

// ---------------- CSR build (once per launch, reused by both layers) ----------------
__global__ void __launch_bounds__(256) deg_kernel(const int* __restrict__ edst, int* __restrict__ deg) {
    int e = blockIdx.x * 256 + threadIdx.x;
    if (e >= EE) return;
    atomicAdd(&deg[edst[e]], 1);
}

__global__ void __launch_bounds__(SCAN_BLK) scan1_kernel(const int* __restrict__ deg,
                                                         int* __restrict__ rowptr, int* __restrict__ bsum) {
    __shared__ int tmp[SCAN_BLK];
    int i = blockIdx.x * SCAN_BLK + threadIdx.x;
    int v = (i < NN) ? deg[i] : 0;
    tmp[threadIdx.x] = v;
    __syncthreads();
    for (int off = 1; off < SCAN_BLK; off <<= 1) {
        int t = (threadIdx.x >= off) ? tmp[threadIdx.x - off] : 0;
        __syncthreads();
        tmp[threadIdx.x] += t;
        __syncthreads();
    }
    if (i < NN) rowptr[i] = tmp[threadIdx.x] - v;   // exclusive
    if (threadIdx.x == SCAN_BLK - 1) bsum[blockIdx.x] = tmp[threadIdx.x];
}

__global__ void scan2_kernel(int* __restrict__ bsum) {
    if (threadIdx.x == 0) {
        int acc = 0;
        for (int b = 0; b < SCAN_NB; b++) { int v = bsum[b]; bsum[b] = acc; acc += v; }
    }
}

__global__ void __launch_bounds__(SCAN_BLK) scan3_kernel(int* __restrict__ rowptr, const int* __restrict__ bsum) {
    int i = blockIdx.x * SCAN_BLK + threadIdx.x;
    if (i < NN) rowptr[i] += bsum[blockIdx.x];
}

__global__ void __launch_bounds__(256) scatter_kernel(const int* __restrict__ esrc, const int* __restrict__ edst,
                                                      const int* __restrict__ rowptr, int* __restrict__ cursor,
                                                      int* __restrict__ csr_src) {
    int e = blockIdx.x * 256 + threadIdx.x;
    if (e >= EE) return;
    int dn = edst[e];
    int pos = atomicAdd(&cursor[dn], 1);
    csr_src[rowptr[dn] + pos] = esrc[e];
}

// ---------------- fused gather-aggregate + softmax-normalize + bias + LN + ReLU ----------------
// one wave per dst node; lane = channel; z and acc accumulate in one pass
// (valid because alpha = e_i / sum e_i: normalize once at the end).
__global__ void __launch_bounds__(256) agg_ln_kernel(
    const int* __restrict__ csr_src, const int* __restrict__ rowptr, const int* __restrict__ deg,
    const float* __restrict__ s, const float* __restrict__ d, const float* __restrict__ h,
    const float* __restrict__ bias, const float* __restrict__ gamma, const float* __restrict__ beta,
    float* __restrict__ out)
{
    const int wid = threadIdx.x >> 6, lane = threadIdx.x & 63;
    const int head = lane >> 4;
    const int n = blockIdx.x * 4 + wid;

    const float dv = d[n * 4 + head];
    float acc, z;
    {   // self-loop (implicit, not stored in CSR)
        float w = __expf(lrelu(s[n * 4 + head] + dv));
        z = w; acc = w * h[n * 64 + lane];
    }
    int j = rowptr[n];
    const int jend = j + deg[n];
    for (; j + 4 <= jend; j += 4) {           // 4-wide index prefetch for MLP
        int s0 = csr_src[j], s1 = csr_src[j + 1], s2 = csr_src[j + 2], s3 = csr_src[j + 3];
        float w0 = __expf(lrelu(s[s0 * 4 + head] + dv));
        float w1 = __expf(lrelu(s[s1 * 4 + head] + dv));
        float w2 = __expf(lrelu(s[s2 * 4 + head] + dv));
        float w3 = __expf(lrelu(s[s3 * 4 + head] + dv));
        acc += w0 * h[s0 * 64 + lane]; z += w0;
        acc += w1 * h[s1 * 64 + lane]; z += w1;
        acc += w2 * h[s2 * 64 + lane]; z += w2;
        acc += w3 * h[s3 * 64 + lane]; z += w3;
    }
    for (; j < jend; j++) {
        int sn = csr_src[j];
        float w = __expf(lrelu(s[sn * 4 + head] + dv));
        acc += w * h[sn * 64 + lane]; z += w;
    }

    float v = acc / (z + 1e-16f) + bias[lane];
    float sum = v, sq = v * v;
#pragma unroll
    for (int o = 32; o; o >>= 1) { sum += __shfl_xor(sum, o); sq += __shfl_xor(sq, o); }
    float mu = sum * (1.f / 64.f);
    float var = sq * (1.f / 64.f) - mu * mu;
    float y = (v - mu) * rsqrtf(var + 1e-5f) * gamma[lane] + beta[lane];
    out[n * 64 + lane] = y > 0.f ? y : 0.f;
}

// ---------------- global mean (hierarchical) + MLP head ----------------
__global__ void __launch_bounds__(256) mean_kernel(const float* __restrict__ xin, float* __restrict__ meanacc) {
    __shared__ float sd[256];
    const int wid = threadIdx.x >> 6, c = threadIdx.x & 63;
    float csum = 0.f;
    for (int grp = blockIdx.x; grp < NN / 4; grp += 512) {
        int n = grp * 4 + wid;
        csum += xin[n * 64 + c];
    }
    sd[threadIdx.x] = csum;
    __syncthreads();
    if (threadIdx.x < 64) {
        fatomic_add(&meanacc[threadIdx.x],
                    sd[threadIdx.x] + sd[64 + threadIdx.x] + sd[128 + threadIdx.x] + sd[192 + threadIdx.x]);
    }
}

__global__ void __launch_bounds__(64) mlp_kernel(
    const float* __restrict__ meanacc,
    const float* __restrict__ Wp1, const float* __restrict__ bp1,
    const float* __restrict__ Wp2, const float* __restrict__ bp2,
    float* __restrict__ out)
{
    __shared__ float mean[64], hid[64];
    int t = threadIdx.x;
    mean[t] = meanacc[t] * (1.f / (float)NN);
    __syncthreads();
    float acc = bp1[t];
#pragma unroll
    for (int i = 0; i < 64; i++) acc += mean[i] * Wp1[i * 64 + t];
    hid[t] = acc > 0.f ? acc : 0.f;
    __syncthreads();
    float o = bp2[t];
#pragma unroll
    for (int i = 0; i < 64; i++) o += hid[i] * Wp2[i * 64 + t];
    out[NN * 64 + t] = o;
}

extern "C" void kernel_launch(void* const* d_in, const int* in_sizes, int n_in,
                              void* d_out, int out_size, void* d_ws, size_t ws_size,
                              hipStream_t stream) {
    const float* x    = (const float*)d_in[0];
    const float* temp = (const float*)d_in[1];
    const int*   ei   = (const int*)d_in[2];
    const float* Wt   = (const float*)d_in[3];
    const float* bt   = (const float*)d_in[4];
    const float* W1   = (const float*)d_in[5];
    const float* as1  = (const float*)d_in[6];
    const float* ad1  = (const float*)d_in[7];
    const float* b1   = (const float*)d_in[8];
    const float* g1   = (const float*)d_in[9];
    const float* be1  = (const float*)d_in[10];
    const float* W2   = (const float*)d_in[11];
    const float* as2  = (const float*)d_in[12];
    const float* ad2  = (const float*)d_in[13];
    const float* b2   = (const float*)d_in[14];
    const float* g2   = (const float*)d_in[15];
    const float* be2  = (const float*)d_in[16];
    const float* Wp1  = (const float*)d_in[17];
    const float* bp1  = (const float*)d_in[18];
    const float* Wp2  = (const float*)d_in[19];
    const float* bp2  = (const float*)d_in[20];

    float* out = (float*)d_out;   // f32 outputs: x2 [100000*64] then ge [64]

    // ws layout: h 6.4Mf | x1 6.4Mf | s 400kf | d 400kf | meanacc 64f |
    //            deg NNi | rowptr NNi | cursor NNi | bsum 256i | csr_src EEi
    float* ws      = (float*)d_ws;
    float* h       = ws;
    float* x1      = ws + 6400000;
    float* sbuf    = ws + 12800000;
    float* dbuf    = sbuf + 400000;
    float* meanacc = dbuf + 400000;
    int*   deg     = (int*)(meanacc + 64);
    int*   rowptr  = deg + NN;
    int*   cursor  = rowptr + NN;
    int*   bsum    = cursor + NN;
    int*   csr_src = bsum + 256;

    const int* esrc = ei;
    const int* edst = ei + EE;

    const int egrid = (EE + 255) / 256;

    // ---- CSR build (shared by both layers) ----
    hipMemsetAsync(deg, 0, NN * sizeof(int), stream);
    hipMemsetAsync(cursor, 0, NN * sizeof(int), stream);
    hipMemsetAsync(meanacc, 0, 64 * sizeof(float), stream);

    deg_kernel<<<egrid, 256, 0, stream>>>(edst, deg);
    scan1_kernel<<<SCAN_NB, SCAN_BLK, 0, stream>>>(deg, rowptr, bsum);
    scan2_kernel<<<1, 64, 0, stream>>>(bsum);
    scan3_kernel<<<SCAN_NB, SCAN_BLK, 0, stream>>>(rowptr, bsum);
    scatter_kernel<<<egrid, 256, 0, stream>>>(esrc, edst, rowptr, cursor, csr_src);

    // ---- layer 1 ----
    feat_kernel<K1, true><<<NN / 4, 256, 0, stream>>>(x, temp, Wt, bt, W1, as1, ad1, h, sbuf, dbuf);
    agg_ln_kernel<<<NN / 4, 256, 0, stream>>>(csr_src, rowptr, deg, sbuf, dbuf, h, b1, g1, be1, x1);

    // ---- layer 2 ----
    feat_kernel<64, false><<<NN / 4, 256, 0, stream>>>(x1, nullptr, nullptr, nullptr, W2, as2, ad2, h, sbuf, dbuf);
    agg_ln_kernel<<<NN / 4, 256, 0, stream>>>(csr_src, rowptr, deg, sbuf, dbuf, h, b2, g2, be2, out);

    // ---- global mean + MLP ----
    mean_kernel<<<512, 256, 0, stream>>>(out, meanacc);
    mlp_kernel<<<1, 64, 0, stream>>>(meanacc, Wp1, bp1, Wp2, bp2, out);
}

// Round 5
// 494.791 us; speedup vs baseline: 3.6031x; 1.2220x over previous
//
#include <hip/hip_runtime.h>
#include <hip/hip_bf16.h>

#define NN    100000
#define EE    1600000
#define INF   56
#define TFEAT 16
#define K1    72

// bucketed CSR build
#define BUCKET_BITS 10
#define BUCKET_NODES (1 << BUCKET_BITS)              // 1024 dst nodes per bucket
#define NB ((NN + BUCKET_NODES - 1) >> BUCKET_BITS)  // 98 buckets
#define BUCKET_CAP 20480                             // mean 16384, sigma ~127 -> +32 sigma
#define S1_EDGES 1024                                // edges per S1 block (4 per thread)

__device__ __forceinline__ void fatomic_add(float* p, float v) {
    __hip_atomic_fetch_add(p, v, __ATOMIC_RELAXED, __HIP_MEMORY_SCOPE_AGENT);
}

__device__ __forceinline__ float lrelu(float v) { return v > 0.f ? v : 0.2f * v; }
__device__ __forceinline__ float bf2f(__hip_bfloat16 b) { return __bfloat162float(b); }

// ---------------- dense feature transform ----------------
// h(bf16) = xc @ W ; s[n,h] = <h_row, a_src[h]> ; d[n,h] = <h_row, a_dst[h]> (f32 logits)
template <int K, bool TEMPORAL, bool IN_BF16>
__global__ void __launch_bounds__(256) feat_kernel(
    const void* __restrict__ xin_, const float* __restrict__ temp,
    const float* __restrict__ Wt, const float* __restrict__ bt,
    const float* __restrict__ W, const float* __restrict__ asrc,
    const float* __restrict__ adst,
    __hip_bfloat16* __restrict__ h, float* __restrict__ s, float* __restrict__ d)
{
    __shared__ float Wl[K * 64];
    __shared__ float xc[4 * K];
    const int tid = threadIdx.x;
    const int n0 = blockIdx.x * 4;

    for (int i = tid; i < K * 64; i += 256) Wl[i] = W[i];

    if (TEMPORAL) {
        const float* xin = (const float*)xin_;
        if (tid < 4 * INF) {
            int node = tid / INF, k = tid - node * INF;
            xc[node * K + k] = xin[(n0 + node) * INF + k];
        }
        if (tid < 4 * TFEAT) {
            int node = tid >> 4, j = tid & 15;
            float tv = temp[n0 + node] * Wt[j] + bt[j];
            xc[node * K + INF + j] = tv > 0.f ? tv : 0.f;
        }
    } else {
        int node = tid >> 6, k = tid & 63;
        if (IN_BF16) {
            const __hip_bfloat16* xin = (const __hip_bfloat16*)xin_;
            xc[node * K + k] = bf2f(xin[(n0 + node) * 64 + k]);
        } else {
            const float* xin = (const float*)xin_;
            xc[node * K + k] = xin[(n0 + node) * 64 + k];
        }
    }
    __syncthreads();

    const int node = tid >> 6, out = tid & 63;
    float acc = 0.f;
#pragma unroll
    for (int k = 0; k < K; k++) acc += xc[node * K + k] * Wl[k * 64 + out];

    const int gn = n0 + node;
    h[gn * 64 + out] = __float2bfloat16(acc);

    const int head = out >> 4, c = out & 15;
    float vs = acc * asrc[head * 16 + c];
    float vd = acc * adst[head * 16 + c];
#pragma unroll
    for (int o = 8; o; o >>= 1) {
        vs += __shfl_down(vs, o, 16);
        vd += __shfl_down(vd, o, 16);
    }
    if (c == 0) { s[gn * 4 + head] = vs; d[gn * 4 + head] = vd; }
}

// ---------------- bucketed CSR build ----------------
// S1: bin edges by dst bucket; chunk-claim per (block,bucket); packed 4B payload.
__global__ void __launch_bounds__(256) csr_s1_kernel(
    const int* __restrict__ esrc, const int* __restrict__ edst,
    int* __restrict__ bucketCnt, int* __restrict__ ebuf)
{
    __shared__ int hist[NB];
    __shared__ int base[NB];
    __shared__ int loff[NB];
    const int tid = threadIdx.x;
    const int e0 = blockIdx.x * S1_EDGES;

    for (int i = tid; i < NB; i += 256) { hist[i] = 0; loff[i] = 0; }
    __syncthreads();

    int val[4], bk[4];
#pragma unroll
    for (int t = 0; t < 4; t++) {
        int e = e0 + t * 256 + tid;
        if (e < EE) {
            int sn = esrc[e], dn = edst[e];
            int b = dn >> BUCKET_BITS;
            bk[t] = b;
            val[t] = ((dn & (BUCKET_NODES - 1)) << 17) | sn;
            atomicAdd(&hist[b], 1);
        } else bk[t] = -1;
    }
    __syncthreads();
    for (int i = tid; i < NB; i += 256)
        base[i] = hist[i] ? atomicAdd(&bucketCnt[i], hist[i]) : 0;
    __syncthreads();
#pragma unroll
    for (int t = 0; t < 4; t++) {
        if (bk[t] >= 0) {
            int pos = atomicAdd(&loff[bk[t]], 1);
            ebuf[bk[t] * BUCKET_CAP + base[bk[t]] + pos] = val[t];
        }
    }
}

// exclusive scan of 98 bucket counts -> csrBase
__global__ void __launch_bounds__(128) csr_scanb_kernel(const int* __restrict__ bucketCnt,
                                                        int* __restrict__ csrBase)
{
    __shared__ int t[128];
    int i = threadIdx.x;
    int v = (i < NB) ? bucketCnt[i] : 0;
    t[i] = v;
    __syncthreads();
    for (int o = 1; o < 128; o <<= 1) {
        int u = (i >= o) ? t[i - o] : 0;
        __syncthreads();
        t[i] += u;
        __syncthreads();
    }
    if (i < NB) csrBase[i] = t[i] - v;
}

// S2: one block per bucket: LDS histogram -> scan -> deg/rowptr (coalesced) -> local scatter.
__global__ void __launch_bounds__(256) csr_s2_kernel(
    const int* __restrict__ bucketCnt, const int* __restrict__ csrBase,
    const int* __restrict__ ebuf,
    int* __restrict__ deg, int* __restrict__ rowptr, int* __restrict__ csr_src)
{
    __shared__ int hist2[BUCKET_NODES];   // histogram, then exclusive scan / cursor
    __shared__ int wsum[4];
    const int b = blockIdx.x;
    const int tid = threadIdx.x;
    const int cnt = bucketCnt[b];
    const int cbase = csrBase[b];
    const int nb0 = b << BUCKET_BITS;
    const int nnodes = min(BUCKET_NODES, NN - nb0);
    const int* seg = ebuf + b * BUCKET_CAP;

    for (int i = tid; i < BUCKET_NODES; i += 256) hist2[i] = 0;
    __syncthreads();
    for (int e = tid; e < cnt; e += 256) atomicAdd(&hist2[seg[e] >> 17], 1);
    __syncthreads();

    // block exclusive scan over 1024 (4 per thread)
    const int i0 = tid * 4;
    int h0 = hist2[i0], h1 = hist2[i0 + 1], h2 = hist2[i0 + 2], h3 = hist2[i0 + 3];
    int local = h0 + h1 + h2 + h3;
    int lane = tid & 63, wid = tid >> 6;
    int inc = local;
    for (int o = 1; o < 64; o <<= 1) {
        int u = __shfl_up(inc, o);
        if (lane >= o) inc += u;
    }
    if (lane == 63) wsum[wid] = inc;
    __syncthreads();
    int wbase = 0;
    for (int w = 0; w < wid; w++) wbase += wsum[w];
    int ebase = wbase + inc - local;       // exclusive prefix for element i0
    __syncthreads();                       // before overwriting hist2

    if (i0 < nnodes)     { deg[nb0 + i0]     = h0; rowptr[nb0 + i0]     = cbase + ebase; }
    if (i0 + 1 < nnodes) { deg[nb0 + i0 + 1] = h1; rowptr[nb0 + i0 + 1] = cbase + ebase + h0; }
    if (i0 + 2 < nnodes) { deg[nb0 + i0 + 2] = h2; rowptr[nb0 + i0 + 2] = cbase + ebase + h0 + h1; }
    if (i0 + 3 < nnodes) { deg[nb0 + i0 + 3] = h3; rowptr[nb0 + i0 + 3] = cbase + ebase + h0 + h1 + h2; }
    hist2[i0]     = ebase;
    hist2[i0 + 1] = ebase + h0;
    hist2[i0 + 2] = ebase + h0 + h1;
    hist2[i0 + 3] = ebase + h0 + h1 + h2;
    __syncthreads();

    for (int e = tid; e < cnt; e += 256) {
        int v = seg[e];
        int pos = atomicAdd(&hist2[v >> 17], 1);
        csr_src[cbase + pos] = v & 0x1FFFF;
    }
}

// ---------------- fused gather-aggregate + softmax + bias + LN + ReLU ----------------
template <bool OUT_BF16>
__global__ void __launch_bounds__(256) agg_ln_kernel(
    const int* __restrict__ csr_src, const int* __restrict__ rowptr, const int* __restrict__ deg,
    const float* __restrict__ s, const float* __restrict__ d, const __hip_bfloat16* __restrict__ h,
    const float* __restrict__ bias, const float* __restrict__ gamma, const float* __restrict__ beta,
    void* __restrict__ out_)
{
    const int wid = threadIdx.x >> 6, lane = threadIdx.x & 63;
    const int head = lane >> 4;
    const int n = blockIdx.x * 4 + wid;

    const float dv = d[n * 4 + head];
    float acc, z;
    {   // self-loop (implicit)
        float w = __expf(lrelu(s[n * 4 + head] + dv));
        z = w; acc = w * bf2f(h[n * 64 + lane]);
    }
    int j = rowptr[n];
    const int jend = j + deg[n];
    for (; j + 4 <= jend; j += 4) {
        int s0 = csr_src[j], s1 = csr_src[j + 1], s2 = csr_src[j + 2], s3 = csr_src[j + 3];
        float w0 = __expf(lrelu(s[s0 * 4 + head] + dv));
        float w1 = __expf(lrelu(s[s1 * 4 + head] + dv));
        float w2 = __expf(lrelu(s[s2 * 4 + head] + dv));
        float w3 = __expf(lrelu(s[s3 * 4 + head] + dv));
        acc += w0 * bf2f(h[s0 * 64 + lane]); z += w0;
        acc += w1 * bf2f(h[s1 * 64 + lane]); z += w1;
        acc += w2 * bf2f(h[s2 * 64 + lane]); z += w2;
        acc += w3 * bf2f(h[s3 * 64 + lane]); z += w3;
    }
    for (; j < jend; j++) {
        int sn = csr_src[j];
        float w = __expf(lrelu(s[sn * 4 + head] + dv));
        acc += w * bf2f(h[sn * 64 + lane]); z += w;
    }

    float v = acc / (z + 1e-16f) + bias[lane];
    float sum = v, sq = v * v;
#pragma unroll
    for (int o = 32; o; o >>= 1) { sum += __shfl_xor(sum, o); sq += __shfl_xor(sq, o); }
    float mu = sum * (1.f / 64.f);
    float var = sq * (1.f / 64.f) - mu * mu;
    float y = (v - mu) * rsqrtf(var + 1e-5f) * gamma[lane] + beta[lane];
    y = y > 0.f ? y : 0.f;
    if (OUT_BF16) ((__hip_bfloat16*)out_)[n * 64 + lane] = __float2bfloat16(y);
    else          ((float*)out_)[n * 64 + lane] = y;
}

// ---------------- global mean (hierarchical) + MLP head ----------------
__global__ void __launch_bounds__(256) mean_kernel(const float* __restrict__ xin, float* __restrict__ meanacc) {
    __shared__ float sd[256];
    const int wid = threadIdx.x >> 6, c = threadIdx.x & 63;
    float csum = 0.f;
    for (int grp = blockIdx.x; grp < NN / 4; grp += 512) {
        int n = grp * 4 + wid;
        csum += xin[n * 64 + c];
    }
    sd[threadIdx.x] = csum;
    __syncthreads();
    if (threadIdx.x < 64) {
        fatomic_add(&meanacc[threadIdx.x],
                    sd[threadIdx.x] + sd[64 + threadIdx.x] + sd[128 + threadIdx.x] + sd[192 + threadIdx.x]);
    }
}

__global__ void __launch_bounds__(64) mlp_kernel(
    const float* __restrict__ meanacc,
    const float* __restrict__ Wp1, const float* __restrict__ bp1,
    const float* __restrict__ Wp2, const float* __restrict__ bp2,
    float* __restrict__ out)
{
    __shared__ float mean[64], hid[64];
    int t = threadIdx.x;
    mean[t] = meanacc[t] * (1.f / (float)NN);
    __syncthreads();
    float acc = bp1[t];
#pragma unroll
    for (int i = 0; i < 64; i++) acc += mean[i] * Wp1[i * 64 + t];
    hid[t] = acc > 0.f ? acc : 0.f;
    __syncthreads();
    float o = bp2[t];
#pragma unroll
    for (int i = 0; i < 64; i++) o += hid[i] * Wp2[i * 64 + t];
    out[NN * 64 + t] = o;
}

extern "C" void kernel_launch(void* const* d_in, const int* in_sizes, int n_in,
                              void* d_out, int out_size, void* d_ws, size_t ws_size,
                              hipStream_t stream) {
    const float* x    = (const float*)d_in[0];
    const float* temp = (const float*)d_in[1];
    const int*   ei   = (const int*)d_in[2];
    const float* Wt   = (const float*)d_in[3];
    const float* bt   = (const float*)d_in[4];
    const float* W1   = (const float*)d_in[5];
    const float* as1  = (const float*)d_in[6];
    const float* ad1  = (const float*)d_in[7];
    const float* b1   = (const float*)d_in[8];
    const float* g1   = (const float*)d_in[9];
    const float* be1  = (const float*)d_in[10];
    const float* W2   = (const float*)d_in[11];
    const float* as2  = (const float*)d_in[12];
    const float* ad2  = (const float*)d_in[13];
    const float* b2   = (const float*)d_in[14];
    const float* g2   = (const float*)d_in[15];
    const float* be2  = (const float*)d_in[16];
    const float* Wp1  = (const float*)d_in[17];
    const float* bp1  = (const float*)d_in[18];
    const float* Wp2  = (const float*)d_in[19];
    const float* bp2  = (const float*)d_in[20];

    float* out = (float*)d_out;   // f32: x2 [100000*64] then ge [64]

    // ws layout (bytes)
    char* w = (char*)d_ws;
    __hip_bfloat16* hb   = (__hip_bfloat16*)w;                 w += (size_t)NN * 64 * 2;  // 12.8 MB
    __hip_bfloat16* x1b  = (__hip_bfloat16*)w;                 w += (size_t)NN * 64 * 2;  // 12.8 MB
    float* sbuf    = (float*)w;                                w += (size_t)NN * 4 * 4;   // 1.6 MB
    float* dbuf    = (float*)w;                                w += (size_t)NN * 4 * 4;   // 1.6 MB
    float* meanacc = (float*)w;                                w += 256;
    int* bucketCnt = (int*)w;                                  w += 512;
    int* csrBase   = (int*)w;                                  w += 512;
    int* deg       = (int*)w;                                  w += (size_t)NN * 4;
    int* rowptr    = (int*)w;                                  w += (size_t)NN * 4;
    int* csr_src   = (int*)w;                                  w += (size_t)EE * 4;       // 6.4 MB
    int* ebuf      = (int*)w;                                  w += (size_t)NB * BUCKET_CAP * 4; // 8 MB

    const int* esrc = ei;
    const int* edst = ei + EE;

    hipMemsetAsync(bucketCnt, 0, 512, stream);
    hipMemsetAsync(meanacc, 0, 256, stream);

    // ---- CSR build (bucketed, L2-local) ----
    csr_s1_kernel<<<(EE + S1_EDGES - 1) / S1_EDGES, 256, 0, stream>>>(esrc, edst, bucketCnt, ebuf);
    csr_scanb_kernel<<<1, 128, 0, stream>>>(bucketCnt, csrBase);
    csr_s2_kernel<<<NB, 256, 0, stream>>>(bucketCnt, csrBase, ebuf, deg, rowptr, csr_src);

    // ---- layer 1 ----
    feat_kernel<K1, true, false><<<NN / 4, 256, 0, stream>>>(x, temp, Wt, bt, W1, as1, ad1, hb, sbuf, dbuf);
    agg_ln_kernel<true><<<NN / 4, 256, 0, stream>>>(csr_src, rowptr, deg, sbuf, dbuf, hb, b1, g1, be1, x1b);

    // ---- layer 2 ----
    feat_kernel<64, false, true><<<NN / 4, 256, 0, stream>>>(x1b, nullptr, nullptr, nullptr, W2, as2, ad2, hb, sbuf, dbuf);
    agg_ln_kernel<false><<<NN / 4, 256, 0, stream>>>(csr_src, rowptr, deg, sbuf, dbuf, hb, b2, g2, be2, out);

    // ---- global mean + MLP ----
    mean_kernel<<<512, 256, 0, stream>>>(out, meanacc);
    mlp_kernel<<<1, 64, 0, stream>>>(meanacc, Wp1, bp1, Wp2, bp2, out);
}